// Round 6
// baseline (36995.993 us; speedup 1.0000x reference)
//
#include <hip/hip_runtime.h>
#include <stdint.h>

#define HH 640
#define BB 128
#define TT 512
#define VV 4097
#define G4 2560      // 4*HH
#define VE 4112      // padded embT cols
#define XS 10240     // per-XCD state floats (640*16)
#define XG 40960     // per-XCD gates floats (640*16*4)
#define NC2 3200     // WJ cols (2560 gates + 640 joint)
#define NC3 4096     // WoutK4 cols (v 0..4095; v=4096 special)

typedef float f32x4v __attribute__((ext_vector_type(4)));

__device__ __forceinline__ float sigm(float x){ return 1.0f/(1.0f+expf(-x)); }

__device__ __forceinline__ unsigned long long packkey(float f, unsigned v){
    unsigned u = __float_as_uint(f);
    unsigned m = (u & 0x80000000u) ? ~u : (u | 0x80000000u);
    return ((unsigned long long)m << 32) | (unsigned long long)(~v);
}

__device__ __forceinline__ float vld(const float* p){ return *(const volatile float*)p; }
__device__ __forceinline__ void  vst(float* p, float v){ *(volatile float*)p = v; }
__device__ __forceinline__ int   vldi(const int* p){ return *(const volatile int*)p; }
__device__ __forceinline__ void  vsti(int* p, int v){ *(volatile int*)p = v; }

// ---------------- init ----------------
__global__ __launch_bounds__(256) void k_init4(const float* __restrict__ h0, const float* __restrict__ c0,
                       float* __restrict__ hcm, float* __restrict__ cs,
                       int* __restrict__ labelP, unsigned long long* __restrict__ slot,
                       int* __restrict__ ctrl){
    int i = blockIdx.x*256 + threadIdx.x;
    if (i < BB*HH){
        int b = i / HH, jj = i % HH;
        int x = b >> 4, bl = b & 15;
        size_t o = (size_t)x*XS + jj*16 + bl;
        hcm[o] = h0[i]; cs[o] = c0[i];
    }
    if (i < BB) slot[i] = 0ULL;
    if (i < 8*32) labelP[i] = 0;
    if (i < 2048) ctrl[i] = 0;
}

// ---------------- one-time transposes ----------------
// WihT[k][u] gate-interleaved u=jj*4+g (for embproj)
__global__ __launch_bounds__(256) void k_tr_gate(const float* __restrict__ W, float* __restrict__ WT){
    int idx = blockIdx.x*256 + threadIdx.x;
    if (idx >= G4*160) return;
    int row = idx / 160, kq = idx % 160;
    int g = row / HH, jj = row % HH;
    float4 f = *reinterpret_cast<const float4*>(W + (size_t)row*HH + kq*4);
    WT[(size_t)(kq*4+0)*G4 + jj*4+g] = f.x;
    WT[(size_t)(kq*4+1)*G4 + jj*4+g] = f.y;
    WT[(size_t)(kq*4+2)*G4 + jj*4+g] = f.z;
    WT[(size_t)(kq*4+3)*G4 + jj*4+g] = f.w;
}
__global__ __launch_bounds__(256) void k_tr640(const float* __restrict__ W, float* __restrict__ WT){
    int idx = blockIdx.x*256 + threadIdx.x;
    if (idx >= HH*160) return;
    int n = idx / 160, kq = idx % 160;
    float4 f = *reinterpret_cast<const float4*>(W + (size_t)n*HH + kq*4);
    WT[(size_t)(kq*4+0)*HH + n] = f.x;
    WT[(size_t)(kq*4+1)*HH + n] = f.y;
    WT[(size_t)(kq*4+2)*HH + n] = f.z;
    WT[(size_t)(kq*4+3)*HH + n] = f.w;
}
__global__ __launch_bounds__(256) void k_tr_embT(const float* __restrict__ emb, float* __restrict__ embT){
    int idx = blockIdx.x*256 + threadIdx.x;
    if (idx >= 160*VE) return;
    int kq = idx / VE, v = idx % VE;
    float4 f = make_float4(0.f,0.f,0.f,0.f);
    if (v < VV) f = *reinterpret_cast<const float4*>(emb + (size_t)v*HH + kq*4);
    embT[(size_t)(kq*4+0)*VE + v] = f.x;
    embT[(size_t)(kq*4+1)*VE + v] = f.y;
    embT[(size_t)(kq*4+2)*VE + v] = f.z;
    embT[(size_t)(kq*4+3)*VE + v] = f.w;
}
// WJ k4-packed combined: cols 0..2559 = Whh (u=jj*4+g), 2560..3199 = Wpred
__global__ __launch_bounds__(256) void k_tr_WJ(const float* __restrict__ Whh, const float* __restrict__ Wpred,
                        float* __restrict__ WJ){
    int idx = blockIdx.x*256 + threadIdx.x;   // NC2*160
    if (idx >= NC2*160) return;
    int u = idx / 160, k4 = idx % 160;
    float4 f;
    if (u < G4){
        int jj = u >> 2, g = u & 3;
        f = *reinterpret_cast<const float4*>(Whh + (size_t)(g*HH+jj)*HH + k4*4);
    } else {
        int n = u - G4;
        f = *reinterpret_cast<const float4*>(Wpred + (size_t)n*HH + k4*4);
    }
    float* d = WJ + ((size_t)k4*NC2 + u)*4;
    d[0]=f.x; d[1]=f.y; d[2]=f.z; d[3]=f.w;
}
// WoutK4 k4-packed, cols 0..4095
__global__ __launch_bounds__(256) void k_tr_woutk4(const float* __restrict__ Wout, float* __restrict__ WK){
    int idx = blockIdx.x*256 + threadIdx.x;   // NC3*160
    if (idx >= NC3*160) return;
    int v = idx / 160, k4 = idx % 160;
    float4 f = *reinterpret_cast<const float4*>(Wout + (size_t)v*HH + k4*4);
    float* d = WK + ((size_t)k4*NC3 + v)*4;
    d[0]=f.x; d[1]=f.y; d[2]=f.z; d[3]=f.w;
}

// ---------------- emb_proj: [VV+1][2560] gate-interleaved; row VV = bias-only ----------------
__global__ __launch_bounds__(256) void k_embproj3(const float* __restrict__ embT,
                          const float* __restrict__ WihT,
                          const float* __restrict__ b_ih, const float* __restrict__ b_hh,
                          float* __restrict__ embproj){
    __shared__ float lwv[HH*16];
    int vt = blockIdx.x / 160, ut = blockIdx.x % 160;
    for (int i=threadIdx.x; i<HH*16; i+=256)
        lwv[i] = WihT[(size_t)(i>>4)*G4 + ut*16 + (i&15)];
    float bias[16];
    #pragma unroll
    for (int u=0;u<16;++u){
        int gu = ut*16+u, jj = gu>>2, g = gu&3;
        bias[u] = b_ih[g*HH+jj] + b_hh[g*HH+jj];
    }
    __syncthreads();
    int v = vt*256 + threadIdx.x;
    float acc[16];
    #pragma unroll
    for (int u=0;u<16;++u) acc[u]=0.f;
    if (v < VV){
        #pragma unroll 2
        for (int k=0;k<HH;++k){
            float e = embT[(size_t)k*VE + v];
            const f32x4v* wr = reinterpret_cast<const f32x4v*>(&lwv[k*16]);
            #pragma unroll
            for (int g=0; g<4; ++g){
                f32x4v w = wr[g];
                #pragma unroll
                for (int ee=0; ee<4; ++ee) acc[g*4+ee] = fmaf(w[ee], e, acc[g*4+ee]);
            }
        }
    }
    if (v <= VV){
        #pragma unroll
        for (int q=0;q<4;++q){
            float4 st = make_float4(acc[q*4+0]+bias[q*4+0], acc[q*4+1]+bias[q*4+1],
                                    acc[q*4+2]+bias[q*4+2], acc[q*4+3]+bias[q*4+3]);
            *reinterpret_cast<float4*>(embproj + (size_t)v*G4 + ut*16 + q*4) = st;
        }
    }
}

// ---------------- enc_proj precompute, layout [t][n][b] ----------------
__global__ __launch_bounds__(128) void k_encprojT2(const float* __restrict__ x,
                          const float* __restrict__ WencT, const float* __restrict__ b_enc,
                          float* __restrict__ encprojT){
    int tile = (blockIdx.x & 7)*2560 + (blockIdx.x >> 3);
    int b   = tile / 160;
    int rem = tile % 160;
    int tt  = rem / 5;
    int nt2 = rem % 5;
    int n = nt2*128 + threadIdx.x;
    float acc[16];
    #pragma unroll
    for (int i=0;i<16;i++) acc[i]=0.f;
    const float* xb = x + (size_t)b*HH*TT + tt*16;
    #pragma unroll 4
    for (int k=0;k<HH;++k){
        float wv = WencT[(size_t)k*HH + n];
        const float4* xp = reinterpret_cast<const float4*>(xb + (size_t)k*TT);
        float4 x0=xp[0], x1=xp[1], x2=xp[2], x3=xp[3];
        acc[0]=fmaf(x0.x,wv,acc[0]);  acc[1]=fmaf(x0.y,wv,acc[1]);
        acc[2]=fmaf(x0.z,wv,acc[2]);  acc[3]=fmaf(x0.w,wv,acc[3]);
        acc[4]=fmaf(x1.x,wv,acc[4]);  acc[5]=fmaf(x1.y,wv,acc[5]);
        acc[6]=fmaf(x1.z,wv,acc[6]);  acc[7]=fmaf(x1.w,wv,acc[7]);
        acc[8]=fmaf(x2.x,wv,acc[8]);  acc[9]=fmaf(x2.y,wv,acc[9]);
        acc[10]=fmaf(x2.z,wv,acc[10]); acc[11]=fmaf(x2.w,wv,acc[11]);
        acc[12]=fmaf(x3.x,wv,acc[12]); acc[13]=fmaf(x3.y,wv,acc[13]);
        acc[14]=fmaf(x3.z,wv,acc[14]); acc[15]=fmaf(x3.w,wv,acc[15]);
    }
    float be = b_enc[n];
    #pragma unroll
    for (int ti=0; ti<16; ++ti)
        encprojT[((size_t)(tt*16+ti)*HH + n)*BB + b] = acc[ti] + be;
}

// ---------------- GCM init: gcm[x][u] = Whh @ h0 (per-XCD gate layout) ----------------
__global__ __launch_bounds__(512) void k_gcm0(const float* __restrict__ WJ, const float* __restrict__ h0,
                       float* __restrict__ gcm){
    __shared__ float stage[XS];
    __shared__ float red[3*128*16];
    int x = blockIdx.x / 20, rr = blockIdx.x % 20;
    int tid = threadIdx.x;
    for (int i=tid; i<XS; i+=512)
        stage[i] = h0[(size_t)(x*16 + (i&15))*HH + (i>>4)];
    __syncthreads();
    const int lane = tid & 127, kq = tid >> 7;
    const int u = rr*128 + lane;
    float acc[16];
    #pragma unroll
    for (int j=0;j<16;++j) acc[j]=0.f;
    const float4* wp = reinterpret_cast<const float4*>(WJ) + (size_t)(kq*40)*NC2 + u;
    for (int it=0; it<40; ++it){
        float4 wj = *wp; wp += NC2;
        const int kb = (kq*40 + it)*4;
        #pragma unroll
        for (int ks=0; ks<4; ++ks){
            float wk = (ks==0)?wj.x:(ks==1)?wj.y:(ks==2)?wj.z:wj.w;
            const float4* hp4 = reinterpret_cast<const float4*>(&stage[(kb+ks)*16]);
            float4 h0v=hp4[0], h1v=hp4[1], h2v=hp4[2], h3v=hp4[3];
            acc[0]=fmaf(wk,h0v.x,acc[0]);  acc[1]=fmaf(wk,h0v.y,acc[1]);
            acc[2]=fmaf(wk,h0v.z,acc[2]);  acc[3]=fmaf(wk,h0v.w,acc[3]);
            acc[4]=fmaf(wk,h1v.x,acc[4]);  acc[5]=fmaf(wk,h1v.y,acc[5]);
            acc[6]=fmaf(wk,h1v.z,acc[6]);  acc[7]=fmaf(wk,h1v.w,acc[7]);
            acc[8]=fmaf(wk,h2v.x,acc[8]);  acc[9]=fmaf(wk,h2v.y,acc[9]);
            acc[10]=fmaf(wk,h2v.z,acc[10]); acc[11]=fmaf(wk,h2v.w,acc[11]);
            acc[12]=fmaf(wk,h3v.x,acc[12]); acc[13]=fmaf(wk,h3v.y,acc[13]);
            acc[14]=fmaf(wk,h3v.z,acc[14]); acc[15]=fmaf(wk,h3v.w,acc[15]);
        }
    }
    if (kq > 0){
        #pragma unroll
        for (int j=0;j<16;++j) red[(kq-1)*2048 + lane*16 + j] = acc[j];
    }
    __syncthreads();
    if (kq == 0){
        #pragma unroll
        for (int j=0;j<16;++j) acc[j] += red[lane*16+j] + red[2048+lane*16+j] + red[4096+lane*16+j];
        int jj = u >> 2, g = u & 3;
        #pragma unroll
        for (int bl=0; bl<16; ++bl)
            gcm[(size_t)x*XG + (jj*16+bl)*4 + g] = acc[bl];
    }
}

// ================= persistent XCD-partitioned kernel =================
__global__ __launch_bounds__(512,1) void k_run(
    const float* __restrict__ WJ, const float* __restrict__ WoutK4,
    const float* __restrict__ WoutRaw, const float* __restrict__ b_pred,
    const float* __restrict__ b_out, const float* __restrict__ embproj,
    const float* __restrict__ encprojT, const int* __restrict__ lens,
    float* hcm, float* h1s, float* cs, float* c1,
    float* gcm, float* gnew, float* jointA,
    unsigned long long* slot, int* labelP, int* ctrl,
    float* dout, int guard)
{
    __shared__ float stage[XS];                 // 40 KB
    __shared__ float red[3*128*16];             // 24 KB
    __shared__ unsigned long long keys[128*16]; // 16 KB
    __shared__ float padf[2048];                //  8 KB (forces 1 block/CU)
    const int tid = threadIdx.x;
    if (guard){ padf[tid & 2047] = (float)guard; stage[0] += padf[1]; }

    int xcd = __builtin_amdgcn_s_getreg(63508) & 7;   // hwreg(HW_REG_XCC_ID=20, 0, 32)

    __shared__ int s_r, s_R;
    if (tid == 0){
        s_r = (int)__hip_atomic_fetch_add((unsigned*)&ctrl[xcd], 1u, __ATOMIC_RELAXED, __HIP_MEMORY_SCOPE_AGENT);
        __hip_atomic_fetch_add((unsigned*)&ctrl[16], 1u, __ATOMIC_RELAXED, __HIP_MEMORY_SCOPE_AGENT);
        long spin = 0;
        while (__hip_atomic_load((unsigned*)&ctrl[16], __ATOMIC_RELAXED, __HIP_MEMORY_SCOPE_AGENT) < 256u
               && spin < 400000000L){ __builtin_amdgcn_s_sleep(1); ++spin; }
        s_R = (int)__hip_atomic_load((unsigned*)&ctrl[xcd], __ATOMIC_RELAXED, __HIP_MEMORY_SCOPE_AGENT);
    }
    __syncthreads();
    const int r = s_r;
    const int R = s_R;
    unsigned* bcp = (unsigned*)&ctrl[32 + xcd*32];
    const int b0 = xcd*16;

    float* hcmX = hcm + (size_t)xcd*XS;
    float* h1X  = h1s + (size_t)xcd*XS;
    float* csX  = cs  + (size_t)xcd*XS;
    float* c1X  = c1  + (size_t)xcd*XS;
    float* gcmX = gcm + (size_t)xcd*XG;
    float* gnewX= gnew+ (size_t)xcd*XG;
    float* jX   = jointA + (size_t)xcd*XS;
    int* labX   = labelP + xcd*32;

    unsigned ph = 0;
    #define LBAR() do { \
        asm volatile("s_waitcnt vmcnt(0) lgkmcnt(0)" ::: "memory"); \
        __syncthreads(); \
        ++ph; \
        if (tid == 0){ \
            __hip_atomic_fetch_add(bcp, 1u, __ATOMIC_RELAXED, __HIP_MEMORY_SCOPE_AGENT); \
            long spin = 0; unsigned tgt = ph * (unsigned)R; \
            while (__hip_atomic_load(bcp, __ATOMIC_RELAXED, __HIP_MEMORY_SCOPE_AGENT) < tgt \
                   && spin < 400000000L){ __builtin_amdgcn_s_sleep(1); ++spin; } \
        } \
        __syncthreads(); \
        asm volatile("" ::: "memory"); \
    } while(0)

    for (int t = 0; t < TT; ++t){
        // ---------- phase 1: select + LSTM nonlin ----------
        for (int u = r*512 + tid; u < XS; u += R*512){
            int jj = u >> 4, bl = u & 15, b = b0 + bl;
            bool mask; int sel = 0, kprev = 0;
            if (t == 0){ mask = true; sel = 0; }
            else {
                unsigned long long key = __hip_atomic_load(&slot[b], __ATOMIC_RELAXED, __HIP_MEMORY_SCOPE_AGENT);
                int k = (int)(~(unsigned)key);
                int lab = vldi(labX + bl);
                mask = ((t-1) >= lens[b]) || (k == 0);
                kprev = k; sel = mask ? lab : k;
            }
            size_t go = (size_t)u*4;
            const float* gs = (mask ? gcmX : gnewX) + go;
            float ghx = vld(gs+0), ghy = vld(gs+1), ghz = vld(gs+2), ghw = vld(gs+3);
            if (!mask){ float* gd = gcmX + go; vst(gd+0,ghx); vst(gd+1,ghy); vst(gd+2,ghz); vst(gd+3,ghw); }
            int erow = (t == 0) ? VV : sel;
            float4 e = reinterpret_cast<const float4*>(embproj)[(size_t)erow*640 + jj];
            float gi = ghx+e.x, gf = ghy+e.y, gg = ghz+e.z, goo = ghw+e.w;
            float ce = mask ? vld(csX+u) : vld(c1X+u);
            float cv = sigm(gf)*ce + sigm(gi)*tanhf(gg);
            float h2 = sigm(goo)*tanhf(cv);
            float he = mask ? vld(hcmX+u) : vld(h1X+u);
            vst(csX+u, ce); vst(c1X+u, cv); vst(hcmX+u, he); vst(h1X+u, h2);
            if (jj == 0){
                if (t > 0) dout[(size_t)b*TT + (t-1)] = mask ? 0.f : (float)kprev;
                vsti(labX + bl, sel);
            }
        }
        LBAR();

        // ---------- phase 2: stage h1; gates+joint GEMM; slot reset ----------
        for (int i = tid; i < XS; i += 512) stage[i] = vld(h1X + i);
        if (r == R-1 && tid < 16)
            __hip_atomic_store(&slot[b0+tid], 0ULL, __ATOMIC_RELAXED, __HIP_MEMORY_SCOPE_AGENT);
        __syncthreads();
        for (int w = r; w < 25; w += R){
            const int lane = tid & 127, kq = tid >> 7;
            const int u = w*128 + lane;
            float acc[16];
            #pragma unroll
            for (int j=0;j<16;++j) acc[j]=0.f;
            const float4* wp = reinterpret_cast<const float4*>(WJ) + (size_t)(kq*40)*NC2 + u;
            for (int it=0; it<40; ++it){
                float4 wj = *wp; wp += NC2;
                const int kb = (kq*40 + it)*4;
                #pragma unroll
                for (int ks=0; ks<4; ++ks){
                    float wk = (ks==0)?wj.x:(ks==1)?wj.y:(ks==2)?wj.z:wj.w;
                    const float4* hp4 = reinterpret_cast<const float4*>(&stage[(kb+ks)*16]);
                    float4 h0v=hp4[0], h1v=hp4[1], h2v=hp4[2], h3v=hp4[3];
                    acc[0]=fmaf(wk,h0v.x,acc[0]);  acc[1]=fmaf(wk,h0v.y,acc[1]);
                    acc[2]=fmaf(wk,h0v.z,acc[2]);  acc[3]=fmaf(wk,h0v.w,acc[3]);
                    acc[4]=fmaf(wk,h1v.x,acc[4]);  acc[5]=fmaf(wk,h1v.y,acc[5]);
                    acc[6]=fmaf(wk,h1v.z,acc[6]);  acc[7]=fmaf(wk,h1v.w,acc[7]);
                    acc[8]=fmaf(wk,h2v.x,acc[8]);  acc[9]=fmaf(wk,h2v.y,acc[9]);
                    acc[10]=fmaf(wk,h2v.z,acc[10]); acc[11]=fmaf(wk,h2v.w,acc[11]);
                    acc[12]=fmaf(wk,h3v.x,acc[12]); acc[13]=fmaf(wk,h3v.y,acc[13]);
                    acc[14]=fmaf(wk,h3v.z,acc[14]); acc[15]=fmaf(wk,h3v.w,acc[15]);
                }
            }
            if (kq > 0){
                #pragma unroll
                for (int j=0;j<16;++j) red[(kq-1)*2048 + lane*16 + j] = acc[j];
            }
            __syncthreads();
            if (kq == 0){
                #pragma unroll
                for (int j=0;j<16;++j) acc[j] += red[lane*16+j] + red[2048+lane*16+j] + red[4096+lane*16+j];
                if (u < G4){
                    int jj = u >> 2, g = u & 3;
                    #pragma unroll
                    for (int bl=0; bl<16; ++bl) vst(gnewX + (size_t)(jj*16+bl)*4 + g, acc[bl]);
                } else {
                    int n = u - G4;
                    float bp = b_pred[n];
                    const float* ep = encprojT + ((size_t)t*HH + n)*BB + b0;
                    #pragma unroll
                    for (int bl=0; bl<16; ++bl){
                        float s = acc[bl] + bp + ep[bl];
                        vst(jX + n*16 + bl, fmaxf(s, 0.f));
                    }
                }
            }
            __syncthreads();
        }
        LBAR();

        // ---------- phase 3: stage joint; logits GEMM; argmax ----------
        for (int i = tid; i < XS; i += 512) stage[i] = vld(jX + i);
        __syncthreads();
        for (int w = r; w < 32; w += R){
            const int lane = tid & 127, kq = tid >> 7;
            const int v = w*128 + lane;
            float acc[16];
            #pragma unroll
            for (int j=0;j<16;++j) acc[j]=0.f;
            const float4* wp = reinterpret_cast<const float4*>(WoutK4) + (size_t)(kq*40)*NC3 + v;
            for (int it=0; it<40; ++it){
                float4 wj = *wp; wp += NC3;
                const int kb = (kq*40 + it)*4;
                #pragma unroll
                for (int ks=0; ks<4; ++ks){
                    float wk = (ks==0)?wj.x:(ks==1)?wj.y:(ks==2)?wj.z:wj.w;
                    const float4* hp4 = reinterpret_cast<const float4*>(&stage[(kb+ks)*16]);
                    float4 h0v=hp4[0], h1v=hp4[1], h2v=hp4[2], h3v=hp4[3];
                    acc[0]=fmaf(wk,h0v.x,acc[0]);  acc[1]=fmaf(wk,h0v.y,acc[1]);
                    acc[2]=fmaf(wk,h0v.z,acc[2]);  acc[3]=fmaf(wk,h0v.w,acc[3]);
                    acc[4]=fmaf(wk,h1v.x,acc[4]);  acc[5]=fmaf(wk,h1v.y,acc[5]);
                    acc[6]=fmaf(wk,h1v.z,acc[6]);  acc[7]=fmaf(wk,h1v.w,acc[7]);
                    acc[8]=fmaf(wk,h2v.x,acc[8]);  acc[9]=fmaf(wk,h2v.y,acc[9]);
                    acc[10]=fmaf(wk,h2v.z,acc[10]); acc[11]=fmaf(wk,h2v.w,acc[11]);
                    acc[12]=fmaf(wk,h3v.x,acc[12]); acc[13]=fmaf(wk,h3v.y,acc[13]);
                    acc[14]=fmaf(wk,h3v.z,acc[14]); acc[15]=fmaf(wk,h3v.w,acc[15]);
                }
            }
            if (kq > 0){
                #pragma unroll
                for (int j=0;j<16;++j) red[(kq-1)*2048 + lane*16 + j] = acc[j];
            }
            __syncthreads();
            if (kq == 0){
                float bo = b_out[v];
                #pragma unroll
                for (int bl=0; bl<16; ++bl){
                    float s = acc[bl] + red[lane*16+bl] + red[2048+lane*16+bl] + red[4096+lane*16+bl] + bo;
                    keys[lane*16+bl] = packkey(s, (unsigned)v);
                }
            }
            __syncthreads();
            if (tid < 16){
                unsigned long long best = 0ULL;
                for (int l=0; l<128; ++l){
                    unsigned long long kk = keys[l*16+tid];
                    if (kk > best) best = kk;
                }
                __hip_atomic_fetch_max(&slot[b0+tid], best, __ATOMIC_RELAXED, __HIP_MEMORY_SCOPE_AGENT);
            }
            __syncthreads();
        }
        if (r == R-1 && tid < 16){     // special v = 4096
            float a = 0.f;
            const float* wr = WoutRaw + (size_t)4096*HH;
            for (int k=0; k<HH; ++k) a = fmaf(wr[k], stage[k*16+tid], a);
            unsigned long long kk = packkey(a + b_out[4096], 4096u);
            __hip_atomic_fetch_max(&slot[b0+tid], kk, __ATOMIC_RELAXED, __HIP_MEMORY_SCOPE_AGENT);
        }
        LBAR();
    }
    #undef LBAR
}

// ---------------- final: emit t=511, hF, cF ----------------
__global__ __launch_bounds__(256) void kFin2(const int* __restrict__ lens,
                        const unsigned long long* __restrict__ slot,
                        const float* __restrict__ hcm, const float* __restrict__ h1s,
                        const float* __restrict__ cs,  const float* __restrict__ c1,
                        float* __restrict__ dout)
{
    int i = blockIdx.x*256 + threadIdx.x;
    if (i >= BB*HH) return;
    int b = i / HH, jj = i % HH;
    int x = b >> 4, bl = b & 15;
    size_t o = (size_t)x*XS + jj*16 + bl;
    unsigned long long key = slot[b];
    int k = (int)(~(unsigned)key);
    bool m = ((TT-1) >= lens[b]) || (k == 0);
    dout[BB*TT + i]         = m ? hcm[o] : h1s[o];
    dout[BB*TT + BB*HH + i] = m ? cs[o]  : c1[o];
    if (i < BB){
        unsigned long long key2 = slot[i];
        int k2 = (int)(~(unsigned)key2);
        bool mm = ((TT-1) >= lens[i]) || (k2 == 0);
        dout[(size_t)i*TT + (TT-1)] = mm ? 0.0f : (float)k2;
    }
}

// ================= fallback (small ws): basic per-step kernels =================
__global__ __launch_bounds__(256) void k_init(const float* __restrict__ h0, const float* __restrict__ c0,
                       float* __restrict__ hs0, float* __restrict__ cso,
                       int* __restrict__ label, unsigned long long* __restrict__ slot){
    int i = blockIdx.x*256 + threadIdx.x;
    if (i < BB*HH){ hs0[i] = h0[i]; cso[i] = c0[i]; }
    if (i < BB){ label[i] = 0; slot[i] = 0ULL; }
}

__global__ __launch_bounds__(256) void k_p1o(
    const float* __restrict__ Whh, const float* __restrict__ Wih,
    const float* __restrict__ embedding,
    const float* __restrict__ b_ih, const float* __restrict__ b_hh,
    const int* __restrict__ lens,
    const float* __restrict__ hs_r, float* __restrict__ hs_w,
    const float* __restrict__ h1_r, float* __restrict__ h1_w,
    float* c_state, float* c1o, int* label,
    const unsigned long long* __restrict__ slot,
    float* __restrict__ out_emit, int t)
{
    int tile = (blockIdx.x & 7)*20 + (blockIdx.x >> 3);
    int jt = tile >> 4, bg = tile & 15;
    int lane = threadIdx.x & 63, w = threadIdx.x >> 6;
    int j = (jt<<6) + lane, b0 = bg<<3;

    bool mask[8]; int kprev[8]; int sel[8];
    #pragma unroll
    for (int bi=0; bi<8; ++bi){
        int b = b0+bi;
        if (t == 0){ mask[bi]=true; sel[bi]=0; kprev[bi]=0; }
        else {
            unsigned long long key = slot[b];
            int k = (int)(~(unsigned)key);
            int lab = label[b];
            bool m = ((t-1) >= lens[b]) || (k == 0);
            mask[bi]=m; kprev[bi]=k; sel[bi] = m ? lab : k;
        }
    }
    float acc[8];
    #pragma unroll
    for (int i=0;i<8;i++) acc[i]=0.f;
    const float* wrow  = Whh + (size_t)(w*HH + j)*HH;
    const float* wrow2 = Wih + (size_t)(w*HH + j)*HH;
    for (int kc=0; kc<HH; kc+=16){
        float wv[16], wv2[16];
        #pragma unroll
        for (int q=0;q<4;q++){
            float4 f = *reinterpret_cast<const float4*>(wrow + kc + q*4);
            wv[q*4+0]=f.x; wv[q*4+1]=f.y; wv[q*4+2]=f.z; wv[q*4+3]=f.w;
            float4 f2 = *reinterpret_cast<const float4*>(wrow2 + kc + q*4);
            wv2[q*4+0]=f2.x; wv2[q*4+1]=f2.y; wv2[q*4+2]=f2.z; wv2[q*4+3]=f2.w;
        }
        #pragma unroll
        for (int bi=0; bi<8; ++bi){
            int b = b0+bi;
            const float* hp0 = hs_r + (size_t)b*HH + kc;
            const float* hp1 = h1_r + (size_t)b*HH + kc;
            float a = acc[bi];
            if (mask[bi]){
                #pragma unroll
                for (int k=0;k<16;k++) a = fmaf(hp0[k], wv[k], a);
            } else {
                #pragma unroll
                for (int k=0;k<16;k++) a = fmaf(hp1[k], wv[k], a);
            }
            if (t > 0){
                const float* ep = embedding + (size_t)sel[bi]*HH + kc;
                #pragma unroll
                for (int k=0;k<16;k++) a = fmaf(ep[k], wv2[k], a);
            }
            acc[bi] = a;
        }
    }
    __shared__ float xch[8][4][64];
    #pragma unroll
    for (int bi=0; bi<8; ++bi)
        xch[bi][w][lane] = acc[bi] + b_ih[w*HH + j] + b_hh[w*HH + j];
    __syncthreads();
    #pragma unroll
    for (int rr=0; rr<2; ++rr){
        int bi = (w<<1) + rr;
        int b  = b0 + bi;
        size_t o = (size_t)b*HH + j;
        float gi = xch[bi][0][lane], gf = xch[bi][1][lane];
        float gg = xch[bi][2][lane], go = xch[bi][3][lane];
        float ce = mask[bi] ? c_state[o] : c1o[o];
        float c2 = sigm(gf)*ce + sigm(gi)*tanhf(gg);
        float h2 = sigm(go)*tanhf(c2);
        float he = mask[bi] ? hs_r[o] : h1_r[o];
        c_state[o] = ce; c1o[o] = c2; hs_w[o] = he; h1_w[o] = h2;
    }
    if (jt == 0 && t > 0 && threadIdx.x < 8){
        int bi = threadIdx.x; int b = b0 + bi;
        out_emit[(size_t)b*TT + (t-1)] = mask[bi] ? 0.0f : (float)kprev[bi];
        label[b] = sel[bi];
    }
}

__global__ __launch_bounds__(128) void k_p2o(
    const float* __restrict__ Wpred, const float* __restrict__ Wenc,
    const float* __restrict__ x, const float* __restrict__ b_enc,
    const float* __restrict__ b_pred, const float* __restrict__ h1,
    float* __restrict__ joint, unsigned long long* __restrict__ slot, int t)
{
    int tile = (blockIdx.x & 7)*20 + (blockIdx.x >> 3);
    int nt = tile / 32, bg = tile % 32;
    int lane = threadIdx.x & 63, w = threadIdx.x >> 6;
    int n = nt*128 + w*64 + lane, b0 = bg*4;
    float acc[4] = {0.f,0.f,0.f,0.f};
    const float* wr  = Wpred + (size_t)n*HH;
    const float* wr2 = Wenc  + (size_t)n*HH;
    for (int kc=0; kc<HH; kc+=16){
        float wv[16], wv2[16];
        #pragma unroll
        for (int q=0;q<4;q++){
            float4 f = *reinterpret_cast<const float4*>(wr + kc + q*4);
            wv[q*4+0]=f.x; wv[q*4+1]=f.y; wv[q*4+2]=f.z; wv[q*4+3]=f.w;
            float4 f2 = *reinterpret_cast<const float4*>(wr2 + kc + q*4);
            wv2[q*4+0]=f2.x; wv2[q*4+1]=f2.y; wv2[q*4+2]=f2.z; wv2[q*4+3]=f2.w;
        }
        #pragma unroll
        for (int bi=0; bi<4; ++bi){
            int b = b0+bi;
            const float* hp = h1 + (size_t)b*HH + kc;
            float a = acc[bi];
            #pragma unroll
            for (int k=0;k<16;k++) a = fmaf(hp[k], wv[k], a);
            const float* xp = x + (size_t)b*HH*TT + (size_t)kc*TT + t;
            #pragma unroll
            for (int k=0;k<16;k++) a = fmaf(xp[(size_t)k*TT], wv2[k], a);
            acc[bi] = a;
        }
    }
    #pragma unroll
    for (int bi=0; bi<4; ++bi){
        int b = b0+bi;
        joint[(size_t)b*HH + n] = fmaxf(acc[bi] + b_pred[n] + b_enc[n], 0.0f);
    }
    if (tile == 0) slot[threadIdx.x] = 0ULL;
}

__global__ __launch_bounds__(256) void k_p3o(
    const float* __restrict__ Wout, const float* __restrict__ b_out,
    const float* __restrict__ joint, unsigned long long* __restrict__ slot)
{
    int tile = (blockIdx.x & 7)*34 + (blockIdx.x >> 3);
    int vt = tile >> 4, bg = tile & 15;
    int lane = threadIdx.x & 63, w = threadIdx.x >> 6;
    int v = vt*256 + w*64 + lane;
    bool valid = v < VV;
    int vv = valid ? v : (VV-1);
    int b0 = bg*8;
    float acc[8];
    #pragma unroll
    for (int i=0;i<8;i++) acc[i]=0.f;
    const float* wr = Wout + (size_t)vv*HH;
    for (int kc=0; kc<HH; kc+=16){
        float wv[16];
        #pragma unroll
        for (int q=0;q<4;q++){
            float4 f = *reinterpret_cast<const float4*>(wr + kc + q*4);
            wv[q*4+0]=f.x; wv[q*4+1]=f.y; wv[q*4+2]=f.z; wv[q*4+3]=f.w;
        }
        #pragma unroll
        for (int bi=0; bi<8; ++bi){
            int b = b0+bi;
            const float* jp = joint + (size_t)b*HH + kc;
            float a = acc[bi];
            #pragma unroll
            for (int k=0;k<16;k++) a = fmaf(jp[k], wv[k], a);
            acc[bi] = a;
        }
    }
    float bofl = b_out[vv];
    __shared__ unsigned long long redo[4][8];
    #pragma unroll
    for (int bi=0; bi<8; ++bi){
        unsigned long long key = valid ? packkey(acc[bi] + bofl, (unsigned)v) : 0ULL;
        #pragma unroll
        for (int off=32; off>0; off>>=1){
            unsigned long long o = __shfl_xor(key, off, 64);
            if (o > key) key = o;
        }
        if (lane == 0) redo[w][bi] = key;
    }
    __syncthreads();
    if (threadIdx.x < 8){
        int bi = threadIdx.x;
        unsigned long long m = redo[0][bi];
        #pragma unroll
        for (int q=1;q<4;q++) if (redo[q][bi] > m) m = redo[q][bi];
        atomicMax(&slot[b0+bi], m);
    }
}

__global__ __launch_bounds__(256) void k_finalo(const int* __restrict__ lens,
                        const unsigned long long* __restrict__ slot,
                        const float* __restrict__ hs_r, const float* __restrict__ h1_r,
                        const float* __restrict__ cso,  const float* __restrict__ c1o,
                        float* __restrict__ dout)
{
    int i = blockIdx.x*256 + threadIdx.x;
    if (i >= BB*HH) return;
    int b = i / HH;
    unsigned long long key = slot[b];
    int k = (int)(~(unsigned)key);
    bool m = ((TT-1) >= lens[b]) || (k == 0);
    dout[BB*TT + i]         = m ? hs_r[i] : h1_r[i];
    dout[BB*TT + BB*HH + i] = m ? cso[i]  : c1o[i];
    if (i < BB){
        unsigned long long key2 = slot[i];
        int k2 = (int)(~(unsigned)key2);
        bool mm = ((TT-1) >= lens[i]) || (k2 == 0);
        dout[(size_t)i*TT + (TT-1)] = mm ? 0.0f : (float)k2;
    }
}

extern "C" void kernel_launch(void* const* d_in, const int* in_sizes, int n_in,
                              void* d_out, int out_size, void* d_ws, size_t ws_size,
                              hipStream_t stream)
{
    const float* x     = (const float*)d_in[0];
    const int*   lens  = (const int*)  d_in[1];
    const float* emb   = (const float*)d_in[2];
    const float* Wih   = (const float*)d_in[3];
    const float* Whh   = (const float*)d_in[4];
    const float* bih   = (const float*)d_in[5];
    const float* bhh   = (const float*)d_in[6];
    const float* Wenc  = (const float*)d_in[7];
    const float* benc  = (const float*)d_in[8];
    const float* Wpred = (const float*)d_in[9];
    const float* bpred = (const float*)d_in[10];
    const float* Wout  = (const float*)d_in[11];
    const float* bout  = (const float*)d_in[12];
    const float* h0    = (const float*)d_in[13];
    const float* c0    = (const float*)d_in[14];
    float* out = (float*)d_out;
    (void)in_sizes; (void)n_in; (void)out_size;

    char* ws = (char*)d_ws;
    size_t off = 0;
    auto alloc = [&](size_t bytes) -> void* {
        void* p = ws + off; off += (bytes + 255) & ~(size_t)255; return p;
    };

    // ---- new-path layout ----
    float* hcm   = (float*)alloc(8*XS*sizeof(float));
    float* h1s   = (float*)alloc(8*XS*sizeof(float));
    float* cs    = (float*)alloc(8*XS*sizeof(float));
    float* c1    = (float*)alloc(8*XS*sizeof(float));
    float* gcm   = (float*)alloc(8*XG*sizeof(float));
    float* gnew  = (float*)alloc(8*XG*sizeof(float));
    float* jointA= (float*)alloc(8*XS*sizeof(float));
    unsigned long long* slot = (unsigned long long*)alloc(BB*sizeof(unsigned long long));
    int* labelP  = (int*)alloc(8*32*sizeof(int));
    int* ctrl    = (int*)alloc(2048*sizeof(int));
    char* Rbig   = (char*)alloc(19001344);
    float* embproj = (float*)alloc((size_t)(VV+1)*G4*sizeof(float));
    float* encprojT= (float*)alloc((size_t)TT*BB*HH*sizeof(float));
    size_t needNew = off;

    if (ws_size >= needNew){
        // temp aliases (phase A)
        float* WihT  = (float*)(Rbig);
        float* embT  = (float*)(Rbig + 6553600);
        float* WencT = (float*)(Rbig + 17080320);
        // perm aliases (phase B, after temps consumed)
        float* WJ     = (float*)(Rbig);
        float* WoutK4 = (float*)(Rbig + 8192000);

        k_init4<<<(BB*HH+255)/256, 256, 0, stream>>>(h0, c0, hcm, cs, labelP, slot, ctrl);
        k_tr_gate<<<(G4*160+255)/256, 256, 0, stream>>>(Wih, WihT);
        k_tr_embT<<<(160*VE+255)/256, 256, 0, stream>>>(emb, embT);
        k_tr640 <<<(HH*160+255)/256, 256, 0, stream>>>(Wenc, WencT);
        k_embproj3<<<17*160, 256, 0, stream>>>(embT, WihT, bih, bhh, embproj);
        k_encprojT2<<<20480, 128, 0, stream>>>(x, WencT, benc, encprojT);
        k_tr_WJ<<<(NC2*160+255)/256, 256, 0, stream>>>(Whh, Wpred, WJ);          // overwrites WihT/embT (consumed)
        k_tr_woutk4<<<(NC3*160+255)/256, 256, 0, stream>>>(Wout, WoutK4);        // overwrites WencT tail (consumed)
        k_gcm0<<<160, 512, 0, stream>>>(WJ, h0, gcm);

        const float* a0 = WJ;      const float* a1 = WoutK4;
        const float* a2 = Wout;    const float* a3 = bpred;
        const float* a4 = bout;    const float* a5 = embproj;
        const float* a6 = encprojT; const int*  a7 = lens;
        float* a8 = hcm;  float* a9 = h1s;  float* a10 = cs;  float* a11 = c1;
        float* a12 = gcm; float* a13 = gnew; float* a14 = jointA;
        unsigned long long* a15 = slot; int* a16 = labelP; int* a17 = ctrl;
        float* a18 = out; int a19 = 0;
        void* args[] = {&a0,&a1,&a2,&a3,&a4,&a5,&a6,&a7,&a8,&a9,&a10,&a11,
                        &a12,&a13,&a14,&a15,&a16,&a17,&a18,&a19};
        hipLaunchCooperativeKernel((const void*)k_run, dim3(256), dim3(512), args, 0, stream);
        kFin2<<<(BB*HH+255)/256, 256, 0, stream>>>(lens, slot, hcm, h1s, cs, c1, out);
        return;
    }

    // -------- fallback: basic per-step path (small ws) --------
    {
        size_t foff = 0;
        auto falloc = [&](size_t bytes) -> void* {
            void* p = ws + foff; foff += (bytes + 255) & ~(size_t)255; return p;
        };
        const size_t BH = (size_t)BB*HH*sizeof(float);
        float* hs0  = (float*)falloc(BH);
        float* hs1  = (float*)falloc(BH);
        float* h1b0 = (float*)falloc(BH);
        float* h1b1 = (float*)falloc(BH);
        float* cso  = (float*)falloc(BH);
        float* c1o  = (float*)falloc(BH);
        float* joint= (float*)falloc(BH);
        int* label  = (int*)falloc(BB*sizeof(int));
        unsigned long long* slotf = (unsigned long long*)falloc(BB*sizeof(unsigned long long));

        k_init<<<(BB*HH+255)/256, 256, 0, stream>>>(h0, c0, hs0, cso, label, slotf);
        float* hsbuf[2] = {hs0, hs1};
        float* h1buf[2] = {h1b0, h1b1};
        for (int t = 0; t < TT; ++t){
            const float* hsr = hsbuf[t & 1];
            float*       hsw = hsbuf[(t+1) & 1];
            const float* h1r = h1buf[(t+1) & 1];
            float*       h1w = h1buf[t & 1];
            k_p1o<<<160, 256, 0, stream>>>(Whh, Wih, emb, bih, bhh, lens,
                                           hsr, hsw, h1r, h1w, cso, c1o, label, slotf, out, t);
            k_p2o<<<160, 128, 0, stream>>>(Wpred, Wenc, x, benc, bpred, h1w, joint, slotf, t);
            k_p3o<<<272, 256, 0, stream>>>(Wout, bout, joint, slotf);
        }
        k_finalo<<<(BB*HH+255)/256, 256, 0, stream>>>(lens, slotf, hsbuf[0], h1buf[1], cso, c1o, out);
    }
}